// Round 1
// baseline (457.774 us; speedup 1.0000x reference)
//
#include <hip/hip_runtime.h>
#include <cstddef>

using f4 = __attribute__((ext_vector_type(4))) float;

constexpr int D_ = 128;     // d_model
constexpr int L_ = 4;       // layers
constexpr int BM = 64;      // tokens per block
constexpr int BK = 16;      // K-chunk staged in LDS
constexpr int LDX = D_ + 4; // padded LDS row stride (keeps float4 alignment, rows 2-way-free)
constexpr int NTHREADS = 256;

struct __align__(16) Smem {
    float xs[BM][LDX];     // x tile (concat second half + layer-0 input)
    float cs[BM][LDX];     // cur tile
    float ws[BK][D_];      // W chunk
    float coef[BM][L_];    // per-token 0/1 mask per depth
};

__global__ __launch_bounds__(NTHREADS, 2)
void moe_fwd(const float* __restrict__ x, const float* __restrict__ Wr,
             const float* __restrict__ Wl, const float* __restrict__ bl,
             const float* __restrict__ We, const float* __restrict__ be,
             float* __restrict__ out)
{
    __shared__ Smem sm;
    const int t  = threadIdx.x;
    const int m0 = blockIdx.x * BM;
    const int tm = t >> 4;   // token group: rows tm*4 .. tm*4+3
    const int tn = t & 15;   // col group:  cols tn*8 .. tn*8+7

    // ---- stage x tile (64x128 f32), coalesced float4 ----
    {
        const f4* gx = reinterpret_cast<const f4*>(x + (size_t)m0 * D_);
        #pragma unroll
        for (int i = 0; i < 8; ++i) {
            int idx = t + i * NTHREADS;       // float4 index in tile
            int row = idx >> 5;               // 32 float4 per row
            int col = (idx & 31) << 2;
            *reinterpret_cast<f4*>(&sm.xs[row][col]) = gx[idx];
        }
    }
    __syncthreads();

    // ---- gates in f64; masks collapse to (gate_d > 0) per depth ----
    if (t < BM) {
        double a0 = 0, a1 = 0, a2 = 0, a3 = 0;
        for (int k = 0; k < D_; ++k) {
            double xv = (double)sm.xs[t][k];
            f4 wr = *reinterpret_cast<const f4*>(&Wr[k * 4]);   // Wr[k][0..3]
            a0 += xv * (double)wr[0];
            a1 += xv * (double)wr[1];
            a2 += xv * (double)wr[2];
            a3 += xv * (double)wr[3];
        }
        sm.coef[t][0] = (a0 > 0.0) ? 1.f : 0.f;
        sm.coef[t][1] = (a1 > 0.0) ? 1.f : 0.f;
        sm.coef[t][2] = (a2 > 0.0) ? 1.f : 0.f;
        sm.coef[t][3] = (a3 > 0.0) ? 1.f : 0.f;
    }
    // coef write -> chunk-loop barriers order it before epilogue reads

    float outreg[4] = {0.f, 0.f, 0.f, 0.f};

    for (int d = 0; d < L_; ++d) {
        const float* Wd = Wl + (size_t)d * (2 * D_) * D_;
        // layer 0 input is [x, x]: fold W0_top + W0_bot -> K=128 (half the FLOPs)
        const int nkc = (d == 0) ? 8 : 16;

        f4 w0, w1;  // W-chunk prefetch registers (2 x float4 / thread = one 8 KB chunk / block)
        {
            const f4* g = reinterpret_cast<const f4*>(Wd);
            if (d == 0) {
                const f4* g2 = reinterpret_cast<const f4*>(Wd + D_ * D_);
                w0 = g[t] + g2[t];
                w1 = g[t + NTHREADS] + g2[t + NTHREADS];
            } else {
                w0 = g[t];
                w1 = g[t + NTHREADS];
            }
        }

        float acc[4][8];
        #pragma unroll
        for (int i = 0; i < 4; ++i)
            #pragma unroll
            for (int j = 0; j < 8; ++j) acc[i][j] = 0.f;

        for (int kc = 0; kc < nkc; ++kc) {
            __syncthreads();   // previous chunk's compute (ws reads) done
            *reinterpret_cast<f4*>(&sm.ws[0][0] + (size_t)t * 4) = w0;
            *reinterpret_cast<f4*>(&sm.ws[0][0] + (size_t)(t + NTHREADS) * 4) = w1;
            __syncthreads();   // ws visible
            if (kc + 1 < nkc) {      // prefetch next chunk; latency hides under compute
                const f4* g = reinterpret_cast<const f4*>(Wd + (size_t)(kc + 1) * BK * D_);
                if (d == 0) {
                    const f4* g2 = reinterpret_cast<const f4*>(Wd + (size_t)(kc + 1) * BK * D_ + D_ * D_);
                    w0 = g[t] + g2[t];
                    w1 = g[t + NTHREADS] + g2[t + NTHREADS];
                } else {
                    w0 = g[t];
                    w1 = g[t + NTHREADS];
                }
            }
            // A-source: k<128 -> cur (x at d==0), k>=128 -> x
            const float (*as)[LDX] = (kc < 8) ? ((d == 0) ? sm.xs : sm.cs) : sm.xs;
            const int col0 = (kc & 7) * BK;
            #pragma unroll
            for (int k4 = 0; k4 < 4; ++k4) {
                f4 av[4];
                #pragma unroll
                for (int i = 0; i < 4; ++i)
                    av[i] = *reinterpret_cast<const f4*>(&as[tm * 4 + i][col0 + k4 * 4]);
                #pragma unroll
                for (int kk = 0; kk < 4; ++kk) {
                    f4 wlo = *reinterpret_cast<const f4*>(&sm.ws[k4 * 4 + kk][tn * 8]);
                    f4 whi = *reinterpret_cast<const f4*>(&sm.ws[k4 * 4 + kk][tn * 8 + 4]);
                    #pragma unroll
                    for (int i = 0; i < 4; ++i) {
                        float a = av[i][kk];
                        acc[i][0] = fmaf(a, wlo[0], acc[i][0]);
                        acc[i][1] = fmaf(a, wlo[1], acc[i][1]);
                        acc[i][2] = fmaf(a, wlo[2], acc[i][2]);
                        acc[i][3] = fmaf(a, wlo[3], acc[i][3]);
                        acc[i][4] = fmaf(a, whi[0], acc[i][4]);
                        acc[i][5] = fmaf(a, whi[1], acc[i][5]);
                        acc[i][6] = fmaf(a, whi[2], acc[i][6]);
                        acc[i][7] = fmaf(a, whi[3], acc[i][7]);
                    }
                }
            }
        }

        // ---- epilogue: bias + relu, estimator dot, masked accumulate, store cur ----
        f4 blo = *reinterpret_cast<const f4*>(&bl[d * D_ + tn * 8]);
        f4 bhi = *reinterpret_cast<const f4*>(&bl[d * D_ + tn * 8 + 4]);
        f4 elo = *reinterpret_cast<const f4*>(&We[d * D_ + tn * 8]);
        f4 ehi = *reinterpret_cast<const f4*>(&We[d * D_ + tn * 8 + 4]);
        const float beb = be[d];
        __syncthreads();   // all ws/xs/cs reads of this layer done before cs overwrite
        #pragma unroll
        for (int i = 0; i < 4; ++i) {
            f4 clo, chi;
            #pragma unroll
            for (int j = 0; j < 4; ++j) {
                clo[j] = fmaxf(acc[i][j] + blo[j], 0.f);
                chi[j] = fmaxf(acc[i][4 + j] + bhi[j], 0.f);
            }
            if (d < L_ - 1) {
                *reinterpret_cast<f4*>(&sm.cs[tm * 4 + i][tn * 8])     = clo;
                *reinterpret_cast<f4*>(&sm.cs[tm * 4 + i][tn * 8 + 4]) = chi;
            }
            float p = clo[0]*elo[0] + clo[1]*elo[1] + clo[2]*elo[2] + clo[3]*elo[3]
                    + chi[0]*ehi[0] + chi[1]*ehi[1] + chi[2]*ehi[2] + chi[3]*ehi[3];
            #pragma unroll
            for (int msk = 1; msk < 16; msk <<= 1) p += __shfl_xor(p, msk, 64);
            if (tn == 0) outreg[i] += sm.coef[tm * 4 + i][d] * (p + beb);
        }
    }

    if (tn == 0) {
        #pragma unroll
        for (int i = 0; i < 4; ++i) out[m0 + tm * 4 + i] = outreg[i];
    }
}

extern "C" void kernel_launch(void* const* d_in, const int* in_sizes, int n_in,
                              void* d_out, int out_size, void* d_ws, size_t ws_size,
                              hipStream_t stream) {
    const float* x  = (const float*)d_in[0];
    const float* Wr = (const float*)d_in[1];
    const float* Wl = (const float*)d_in[2];
    const float* bl = (const float*)d_in[3];
    const float* We = (const float*)d_in[4];
    const float* be = (const float*)d_in[5];
    float* out = (float*)d_out;
    const int B = in_sizes[0] / D_;          // 131072
    moe_fwd<<<dim3(B / BM), dim3(NTHREADS), 0, stream>>>(x, Wr, Wl, bl, We, be, out);
}

// Round 2
// 77.025 us; speedup vs baseline: 5.9432x; 5.9432x over previous
//
#include <hip/hip_runtime.h>
#include <cstddef>

typedef float f4 __attribute__((ext_vector_type(4)));
typedef __bf16 bf16x8 __attribute__((ext_vector_type(8)));
typedef __bf16 bf16x4 __attribute__((ext_vector_type(4)));
typedef float f32x16 __attribute__((ext_vector_type(16)));

constexpr int D_ = 128;       // d_model
constexpr int LAYERS = 4;
constexpr int BM = 128;       // tokens per block
constexpr int NT = 512;       // threads (8 waves: 2 n-rows x 4 token-cols)
constexpr int ROWB = 512;     // LDS row stride bytes (256 bf16)
constexpr int WT_LAYER = 128 * 256;   // bf16 elems per layer in d_ws

// XOR swizzle: spreads 16B column slots across banks for stride-512B rows (T2/G4).
__device__ __forceinline__ int swz(int row, int woff) {
    return row * ROWB + (woff ^ ((row & 15) << 4));
}

// prep: build bf16 W^T  wt[d][n][ks]  (ks<128 = cur part, ks>=128 = x part).
// Layer 0: concat([x,x]) -> fold top+bot into ks in [128,256), zeros below.
__global__ void prep(const float* __restrict__ Wl, __bf16* __restrict__ wt) {
    int idx = blockIdx.x * 256 + threadIdx.x;   // flat [d][n][ks], 4*128*256
    int d = idx >> 15, rem = idx & 32767;
    int n = rem >> 8, ks = rem & 255;
    float v;
    if (d == 0)
        v = (ks < 128) ? 0.f
                       : (Wl[(size_t)(ks - 128) * D_ + n] + Wl[(size_t)ks * D_ + n]);
    else
        v = Wl[(size_t)d * 32768 + (size_t)ks * D_ + n];
    wt[idx] = (__bf16)v;
}

__global__ __launch_bounds__(NT, 2)
void moe_fwd(const float* __restrict__ x, const float* __restrict__ Wr,
             const __bf16* __restrict__ wt, const float* __restrict__ bl,
             const float* __restrict__ We, const float* __restrict__ be,
             float* __restrict__ out)
{
    extern __shared__ char sm[];
    char* Ab = sm;                      // 64 KB: A tile [128 tok][256 ks] bf16 swizzled
    char* Wb = sm + 65536;              // 64 KB: W^T tile [128 n][256 ks] bf16 swizzled
    float* PR = (float*)(sm + 131072);  // [2][128] per-nw pred partials

    const int t    = threadIdx.x;
    const int m0   = blockIdx.x * BM;
    const int lane = t & 63, w = t >> 6;
    const int nw   = w >> 2;            // 0..1  (n-half)
    const int tw   = w & 3;             // 0..3  (token quarter)
    const int lo5  = lane & 31, hi = lane >> 5;
    const int token = tw * 32 + lo5;
    const int hi16  = hi * 16;

    // ---- stage x -> A tile cols [128,256) as bf16 (coalesced 32B/lane reads) ----
    #pragma unroll
    for (int i = 0; i < 4; ++i) {
        int u = i * NT + t;                  // 2048 units of 8 bf16
        int row = u >> 4, s8 = u & 15;
        const f4* gx = (const f4*)(x + (size_t)(m0 + row) * D_ + s8 * 8);
        f4 lo = gx[0], hp = gx[1];
        bf16x8 v;
        v[0] = (__bf16)lo[0]; v[1] = (__bf16)lo[1]; v[2] = (__bf16)lo[2]; v[3] = (__bf16)lo[3];
        v[4] = (__bf16)hp[0]; v[5] = (__bf16)hp[1]; v[6] = (__bf16)hp[2]; v[7] = (__bf16)hp[3];
        *(bf16x8*)(Ab + swz(row, 256 + s8 * 16)) = v;
    }
    // ---- stage W^T layer 0 (register-staged, swizzled ds_write) ----
    {
        const f4* gw = (const f4*)(wt);
        #pragma unroll
        for (int i = 0; i < 8; ++i) {
            int u = i * NT + t;              // 4096 units of 16B
            f4 v = gw[u];
            int n = u >> 5, sl = u & 31;
            *(f4*)(Wb + swz(n, sl * 16)) = v;
        }
    }
    // ---- gates in f64 (identical accumulation order to the passing R1 kernel) ----
    float cf0 = 0, cf1 = 0, cf2 = 0, cf3 = 0, outc = 0;
    if (t < 128) {
        const float* xr = x + (size_t)(m0 + t) * D_;
        double a0 = 0, a1 = 0, a2 = 0, a3 = 0;
        for (int k = 0; k < D_; ++k) {
            double xv = (double)xr[k];
            f4 wr = *(const f4*)(Wr + k * 4);
            a0 += xv * (double)wr[0]; a1 += xv * (double)wr[1];
            a2 += xv * (double)wr[2]; a3 += xv * (double)wr[3];
        }
        cf0 = a0 > 0.0 ? 1.f : 0.f; cf1 = a1 > 0.0 ? 1.f : 0.f;
        cf2 = a2 > 0.0 ? 1.f : 0.f; cf3 = a3 > 0.0 ? 1.f : 0.f;
    }
    __syncthreads();

    const int nrow0 = nw * 64 + lo5;     // wave's n rows (A-operand = W^T)
    const int nrow1 = nrow0 + 32;

    #pragma unroll
    for (int d = 0; d < LAYERS; ++d) {
        const float cfd = (d == 0) ? cf0 : (d == 1) ? cf1 : (d == 2) ? cf2 : cf3;
        f32x16 acc[2];
        #pragma unroll
        for (int m = 0; m < 2; ++m)
            #pragma unroll
            for (int j = 0; j < 16; ++j) acc[m][j] = 0.f;

        const int kstart = (d == 0) ? 8 : 0;   // layer 0: K=128 (x half only)
        #pragma unroll
        for (int ks = 0; ks < 16; ++ks) {
            if (ks < kstart) continue;         // d unrolled -> compile-time
            int wo = ks * 32 + hi16;
            bf16x8 a0 = *(const bf16x8*)(Wb + swz(nrow0, wo));
            bf16x8 a1 = *(const bf16x8*)(Wb + swz(nrow1, wo));
            bf16x8 bt = *(const bf16x8*)(Ab + swz(token, wo));
            acc[0] = __builtin_amdgcn_mfma_f32_32x32x16_bf16(a0, bt, acc[0], 0, 0, 0);
            acc[1] = __builtin_amdgcn_mfma_f32_32x32x16_bf16(a1, bt, acc[1], 0, 0, 0);
        }
        __syncthreads();   // all LDS reads of this layer done

        // ---- epilogue: bias+relu (fp32), estimator dot, cur -> A (bf16) ----
        // D[n][token]: token = lane&31 (col), n = (reg&3)+8*(reg>>2)+4*hi (+32*m+64*nw)
        float p = 0.f;
        #pragma unroll
        for (int m = 0; m < 2; ++m) {
            #pragma unroll
            for (int rg = 0; rg < 4; ++rg) {
                int nb = nw * 64 + m * 32 + rg * 8 + hi * 4;
                f4 bv = *(const f4*)(bl + d * D_ + nb);
                f4 ev = *(const f4*)(We + d * D_ + nb);
                float c0 = fmaxf(acc[m][rg * 4 + 0] + bv[0], 0.f);
                float c1 = fmaxf(acc[m][rg * 4 + 1] + bv[1], 0.f);
                float c2 = fmaxf(acc[m][rg * 4 + 2] + bv[2], 0.f);
                float c3 = fmaxf(acc[m][rg * 4 + 3] + bv[3], 0.f);
                p += c0 * ev[0] + c1 * ev[1] + c2 * ev[2] + c3 * ev[3];
                if (d < LAYERS - 1) {
                    bf16x4 cc;
                    cc[0] = (__bf16)c0; cc[1] = (__bf16)c1;
                    cc[2] = (__bf16)c2; cc[3] = (__bf16)c3;
                    *(bf16x4*)(Ab + swz(token, nb * 2)) = cc;
                }
            }
        }
        p += __shfl_xor(p, 32, 64);              // combine hi halves (same token)
        if (lane < 32) PR[nw * 128 + token] = p; // per-n-half partial

        if (d < LAYERS - 1) {                    // stage next layer's W^T
            const f4* gw = (const f4*)(wt + (size_t)(d + 1) * WT_LAYER);
            #pragma unroll
            for (int i = 0; i < 8; ++i) {
                int u = i * NT + t;
                f4 v = gw[u];
                int n = u >> 5, sl = u & 31;
                *(f4*)(Wb + swz(n, sl * 16)) = v;
            }
        }
        __syncthreads();   // cur, PR, next W visible

        if (t < 128) outc += cfd * (PR[t] + PR[128 + t] + be[d]);
    }

    if (t < 128) out[m0 + t] = outc;
}

extern "C" void kernel_launch(void* const* d_in, const int* in_sizes, int n_in,
                              void* d_out, int out_size, void* d_ws, size_t ws_size,
                              hipStream_t stream) {
    const float* x  = (const float*)d_in[0];
    const float* Wr = (const float*)d_in[1];
    const float* Wl = (const float*)d_in[2];
    const float* bl = (const float*)d_in[3];
    const float* We = (const float*)d_in[4];
    const float* be = (const float*)d_in[5];
    float* out = (float*)d_out;
    __bf16* wt = (__bf16*)d_ws;                 // 256 KB of scratch
    const int B = in_sizes[0] / D_;             // 131072

    prep<<<dim3(LAYERS * 128 * 256 / 256), dim3(256), 0, stream>>>(Wl, wt);
    moe_fwd<<<dim3(B / BM), dim3(NT), 132096, stream>>>(x, Wr, wt, bl, We, be, out);
}

// Round 3
// 74.474 us; speedup vs baseline: 6.1468x; 1.0343x over previous
//
#include <hip/hip_runtime.h>
#include <cstddef>

typedef float f4 __attribute__((ext_vector_type(4)));
typedef float f2 __attribute__((ext_vector_type(2)));
typedef __bf16 bf16x8 __attribute__((ext_vector_type(8)));
typedef __bf16 bf16x4 __attribute__((ext_vector_type(4)));
typedef float f32x16 __attribute__((ext_vector_type(16)));

constexpr int D_ = 128;     // d_model
constexpr int LAYERS = 4;
constexpr int BM = 128;     // tokens per block
constexpr int NT = 256;     // 4 waves: nw (n-half) x tw (token-half)
constexpr int ROWB = 512;   // A-tile row stride bytes (256 bf16)

// XOR swizzle (T2/G4): spreads 16B slots across banks for stride-512B rows.
__device__ __forceinline__ int swz(int row, int woff) {
    return row * ROWB + (woff ^ ((row & 15) << 4));
}

// prep: W^T in MFMA A-fragment order.
// wt2[((d*4 + nf)*16 + kc)*512 + lane*8 + j] = W^T[d][n = nf*32 + (lane&31)]
//                                                  [k = kc*16 + (lane>>5)*8 + j]
// Layer 0 folds concat([x,x]): top+bot summed into k in [128,256), zeros below.
__global__ void prep(const float* __restrict__ Wl, __bf16* __restrict__ wt2) {
    int idx = blockIdx.x * 256 + threadIdx.x;        // 4*4*16*512 = 131072
    int j = idx & 7, lane = (idx >> 3) & 63, kc = (idx >> 9) & 15,
        nf = (idx >> 13) & 3, d = idx >> 15;
    int n  = nf * 32 + (lane & 31);
    int ks = kc * 16 + (lane >> 5) * 8 + j;
    float v;
    if (d == 0)
        v = (ks < 128) ? 0.f
                       : (Wl[(size_t)(ks - 128) * D_ + n] + Wl[(size_t)ks * D_ + n]);
    else
        v = Wl[(size_t)d * 2 * D_ * D_ + (size_t)ks * D_ + n];
    wt2[idx] = (__bf16)v;
}

__global__ __launch_bounds__(NT, 2)
void moe_fwd(const float* __restrict__ x, const float* __restrict__ Wr,
             const __bf16* __restrict__ wt2, const float* __restrict__ bl,
             const float* __restrict__ We, const float* __restrict__ be,
             float* __restrict__ out)
{
    __shared__ char Ab[BM * ROWB];     // 64 KB: [token][256 k] bf16 swizzled (k<128 cur, k>=128 x)
    __shared__ float PR[2][BM];        // per-n-half estimator partials
    __shared__ float CSM[BM][4];       // per-token 0/1 gate coefs

    const int t    = threadIdx.x;
    const int m0   = blockIdx.x * BM;
    const int lane = t & 63, w = t >> 6;
    const int nw   = w >> 1;            // n-half   (n in [nw*64, nw*64+64))
    const int tw   = w & 1;             // token-half
    const int lo5  = lane & 31, hi = lane >> 5;
    const int hi16 = hi * 16;
    const int tok0 = tw * 64 + lo5, tok1 = tok0 + 32;

    // ---- stage x -> Ab cols [128,256) as bf16 (coalesced 32B/lane reads) ----
    #pragma unroll
    for (int i = 0; i < 8; ++i) {
        int u = i * NT + t;                 // 2048 units of 8 bf16
        int row = u >> 4, s8 = u & 15;
        const f4* gx = (const f4*)(x + (size_t)(m0 + row) * D_ + s8 * 8);
        f4 lo = gx[0], hp = gx[1];
        bf16x8 v;
        v[0] = (__bf16)lo[0]; v[1] = (__bf16)lo[1]; v[2] = (__bf16)lo[2]; v[3] = (__bf16)lo[3];
        v[4] = (__bf16)hp[0]; v[5] = (__bf16)hp[1]; v[6] = (__bf16)hp[2]; v[7] = (__bf16)hp[3];
        *(bf16x8*)(Ab + swz(row, 256 + s8 * 16)) = v;
    }

    // ---- gates in f64, 2 gates/thread (same accumulation order as passing R1/R2) ----
    {
        int token = t & 127, pair = t >> 7;          // pair 0: gates 0,1; pair 1: gates 2,3
        const float* xr  = x + (size_t)(m0 + token) * D_;
        const float* wrp = Wr + 2 * pair;
        double a0 = 0, a1 = 0;
        for (int k = 0; k < D_; ++k) {
            double xv = (double)xr[k];
            f2 wv = *(const f2*)(wrp + k * 4);
            a0 += xv * (double)wv[0];
            a1 += xv * (double)wv[1];
        }
        CSM[token][2 * pair]     = a0 > 0.0 ? 1.f : 0.f;
        CSM[token][2 * pair + 1] = a1 > 0.0 ? 1.f : 0.f;
    }
    float outc = 0.f;
    __syncthreads();

    #pragma unroll
    for (int d = 0; d < LAYERS; ++d) {
        const int kstart = (d == 0) ? 8 : 0;   // layer 0: K=128 (x half only)

        // ---- A-operand (W^T) frags: global(L2) -> 128 VGPR, fully coalesced ----
        bf16x8 wf[2][16];
        {
            const __bf16* wb = wt2 + ((size_t)(d * 4 + nw * 2) * 16) * 512 + lane * 8;
            #pragma unroll
            for (int m = 0; m < 2; ++m)
                #pragma unroll
                for (int kc = 0; kc < 16; ++kc)
                    if (kc >= kstart)
                        wf[m][kc] = *(const bf16x8*)(wb + (size_t)(m * 16 + kc) * 512);
        }

        f32x16 acc[2][2];
        #pragma unroll
        for (int m = 0; m < 2; ++m)
            #pragma unroll
            for (int tf = 0; tf < 2; ++tf)
                #pragma unroll
                for (int j = 0; j < 16; ++j) acc[m][tf][j] = 0.f;

        #pragma unroll
        for (int ks = 0; ks < 16; ++ks) {
            if (ks < kstart) continue;          // compile-time (d unrolled)
            int wo = ks * 32 + hi16;
            bf16x8 b0 = *(const bf16x8*)(Ab + swz(tok0, wo));
            bf16x8 b1 = *(const bf16x8*)(Ab + swz(tok1, wo));
            acc[0][0] = __builtin_amdgcn_mfma_f32_32x32x16_bf16(wf[0][ks], b0, acc[0][0], 0, 0, 0);
            acc[0][1] = __builtin_amdgcn_mfma_f32_32x32x16_bf16(wf[0][ks], b1, acc[0][1], 0, 0, 0);
            acc[1][0] = __builtin_amdgcn_mfma_f32_32x32x16_bf16(wf[1][ks], b0, acc[1][0], 0, 0, 0);
            acc[1][1] = __builtin_amdgcn_mfma_f32_32x32x16_bf16(wf[1][ks], b1, acc[1][1], 0, 0, 0);
        }
        __syncthreads();   // all Ab reads of this layer done before cur overwrite

        // ---- epilogue: bias+relu (fp32), estimator dot, cur -> Ab (bf16) ----
        // D[n][token]: token = lane&31, n = (reg&3) + 8*(reg>>2) + 4*hi (+32m+64nw)
        float p0 = 0.f, p1 = 0.f;
        #pragma unroll
        for (int m = 0; m < 2; ++m) {
            #pragma unroll
            for (int rg = 0; rg < 4; ++rg) {
                int nb = nw * 64 + m * 32 + rg * 8 + hi * 4;
                f4 bv = *(const f4*)(bl + d * D_ + nb);
                f4 ev = *(const f4*)(We + d * D_ + nb);
                #pragma unroll
                for (int tf = 0; tf < 2; ++tf) {
                    float c0 = fmaxf(acc[m][tf][rg * 4 + 0] + bv[0], 0.f);
                    float c1 = fmaxf(acc[m][tf][rg * 4 + 1] + bv[1], 0.f);
                    float c2 = fmaxf(acc[m][tf][rg * 4 + 2] + bv[2], 0.f);
                    float c3 = fmaxf(acc[m][tf][rg * 4 + 3] + bv[3], 0.f);
                    float pp = c0 * ev[0] + c1 * ev[1] + c2 * ev[2] + c3 * ev[3];
                    if (tf == 0) p0 += pp; else p1 += pp;
                    if (d < LAYERS - 1) {
                        bf16x4 cc;
                        cc[0] = (__bf16)c0; cc[1] = (__bf16)c1;
                        cc[2] = (__bf16)c2; cc[3] = (__bf16)c3;
                        int token = tw * 64 + tf * 32 + lo5;
                        *(bf16x4*)(Ab + swz(token, nb * 2)) = cc;
                    }
                }
            }
        }
        p0 += __shfl_xor(p0, 32, 64);
        p1 += __shfl_xor(p1, 32, 64);
        if (lane < 32) {
            PR[nw][tw * 64 + lo5]      = p0;
            PR[nw][tw * 64 + 32 + lo5] = p1;
        }
        __syncthreads();   // cur + PR visible

        if (t < BM)
            outc += CSM[t][d] * (PR[0][t] + PR[1][t] + be[d]);
    }

    if (t < BM) out[m0 + t] = outc;
}

extern "C" void kernel_launch(void* const* d_in, const int* in_sizes, int n_in,
                              void* d_out, int out_size, void* d_ws, size_t ws_size,
                              hipStream_t stream) {
    const float* x  = (const float*)d_in[0];
    const float* Wr = (const float*)d_in[1];
    const float* Wl = (const float*)d_in[2];
    const float* bl = (const float*)d_in[3];
    const float* We = (const float*)d_in[4];
    const float* be = (const float*)d_in[5];
    float* out = (float*)d_out;
    __bf16* wt2 = (__bf16*)d_ws;                // 256 KB scratch
    const int B = in_sizes[0] / D_;             // 131072

    prep<<<dim3(512), dim3(256), 0, stream>>>(Wl, wt2);
    moe_fwd<<<dim3(B / BM), dim3(NT), 0, stream>>>(x, Wr, wt2, bl, We, be, out);
}

// Round 4
// 56.371 us; speedup vs baseline: 8.1207x; 1.3211x over previous
//
#include <hip/hip_runtime.h>
#include <cstddef>

typedef float f4 __attribute__((ext_vector_type(4)));
typedef __bf16 bf16x8 __attribute__((ext_vector_type(8)));
typedef __bf16 bf16x4 __attribute__((ext_vector_type(4)));
typedef float f32x16 __attribute__((ext_vector_type(16)));

constexpr int D_ = 128;     // d_model
constexpr int LAYERS = 4;
constexpr int BM = 128;     // tokens per block
constexpr int NT = 256;     // 4 waves: nw (n-half) x tw (token-half)
constexpr int ROWB = 512;   // A-tile row stride bytes (256 bf16)

// XOR swizzle (T2/G4): spreads 16B slots across banks for stride-512B rows.
__device__ __forceinline__ int swz(int row, int woff) {
    return row * ROWB + (woff ^ ((row & 15) << 4));
}

// prep: W^T in MFMA A-fragment order.
// wt2[((d*4 + nf)*16 + kc)*512 + lane*8 + j] = W^T[d][n = nf*32 + (lane&31)]
//                                                  [k = kc*16 + (lane>>5)*8 + j]
// Layer 0 folds concat([x,x]): top+bot summed into k in [128,256), zeros below.
__global__ void prep(const float* __restrict__ Wl, __bf16* __restrict__ wt2) {
    int idx = blockIdx.x * 256 + threadIdx.x;        // 4*4*16*512 = 131072
    int j = idx & 7, lane = (idx >> 3) & 63, kc = (idx >> 9) & 15,
        nf = (idx >> 13) & 3, d = idx >> 15;
    int n  = nf * 32 + (lane & 31);
    int ks = kc * 16 + (lane >> 5) * 8 + j;
    float v;
    if (d == 0)
        v = (ks < 128) ? 0.f
                       : (Wl[(size_t)(ks - 128) * D_ + n] + Wl[(size_t)ks * D_ + n]);
    else
        v = Wl[(size_t)d * 2 * D_ * D_ + (size_t)ks * D_ + n];
    wt2[idx] = (__bf16)v;
}

__global__ __launch_bounds__(NT, 2)
void moe_fwd(const float* __restrict__ x, const float* __restrict__ Wr,
             const __bf16* __restrict__ wt2, const float* __restrict__ bl,
             const float* __restrict__ We, const float* __restrict__ be,
             float* __restrict__ out)
{
    __shared__ char Ab[BM * ROWB];     // 64 KB: [token][256 k] bf16 swizzled (k<128 cur, k>=128 x)
    __shared__ float PR[2][BM];        // per-n-half estimator partials
    __shared__ float CSM[BM][4];       // per-token 0/1 gate coefs

    const int t    = threadIdx.x;
    const int m0   = blockIdx.x * BM;
    const int lane = t & 63, w = t >> 6;
    const int nw   = w >> 1;            // n-half   (n in [nw*64, nw*64+64))
    const int tw   = w & 1;             // token-half
    const int lo5  = lane & 31, hi = lane >> 5;
    const int hi16 = hi * 16;
    const int tok0 = tw * 64 + lo5, tok1 = tok0 + 32;
    const int grp  = t >> 4, il = t & 15;   // 16 lanes per token row

    // ---- per-lane Wr rows (k = il*8 .. il*8+7), held in regs for gate dots ----
    f4 wrv[8];
    #pragma unroll
    for (int j = 0; j < 8; ++j)
        wrv[j] = *(const f4*)(Wr + (il * 8 + j) * 4);

    // ---- fused: stage x -> Ab (bf16, swizzled) + f64 gates from same registers ----
    // iteration i: this thread handles token row 16i + grp, cols il*8 .. il*8+7.
    #pragma unroll
    for (int i = 0; i < 8; ++i) {
        const int row = i * 16 + grp;
        const f4* gx = (const f4*)(x + (size_t)(m0 + row) * D_ + il * 8);
        f4 lo = gx[0], hp = gx[1];
        bf16x8 v;
        v[0] = (__bf16)lo[0]; v[1] = (__bf16)lo[1]; v[2] = (__bf16)lo[2]; v[3] = (__bf16)lo[3];
        v[4] = (__bf16)hp[0]; v[5] = (__bf16)hp[1]; v[6] = (__bf16)hp[2]; v[7] = (__bf16)hp[3];
        *(bf16x8*)(Ab + swz(row, 256 + il * 16)) = v;

        double a0 = 0, a1 = 0, a2 = 0, a3 = 0;
        #pragma unroll
        for (int j = 0; j < 4; ++j) {
            double xv = (double)lo[j];
            a0 += xv * (double)wrv[j][0]; a1 += xv * (double)wrv[j][1];
            a2 += xv * (double)wrv[j][2]; a3 += xv * (double)wrv[j][3];
        }
        #pragma unroll
        for (int j = 0; j < 4; ++j) {
            double xv = (double)hp[j];
            a0 += xv * (double)wrv[4 + j][0]; a1 += xv * (double)wrv[4 + j][1];
            a2 += xv * (double)wrv[4 + j][2]; a3 += xv * (double)wrv[4 + j][3];
        }
        #pragma unroll
        for (int s = 1; s < 16; s <<= 1) {   // 16-lane f64 tree reduce
            a0 += __shfl_xor(a0, s, 16);
            a1 += __shfl_xor(a1, s, 16);
            a2 += __shfl_xor(a2, s, 16);
            a3 += __shfl_xor(a3, s, 16);
        }
        if (il == 0) {
            f4 c;
            c[0] = a0 > 0.0 ? 1.f : 0.f; c[1] = a1 > 0.0 ? 1.f : 0.f;
            c[2] = a2 > 0.0 ? 1.f : 0.f; c[3] = a3 > 0.0 ? 1.f : 0.f;
            *(f4*)(&CSM[row][0]) = c;
        }
    }

    float outc = 0.f;
    __syncthreads();

    #pragma unroll
    for (int d = 0; d < LAYERS; ++d) {
        const int kstart = (d == 0) ? 8 : 0;   // layer 0: K=128 (x half only)

        // ---- A-operand (W^T) frags: global(L2) -> 128 VGPR, fully coalesced ----
        bf16x8 wf[2][16];
        {
            const __bf16* wb = wt2 + ((size_t)(d * 4 + nw * 2) * 16) * 512 + lane * 8;
            #pragma unroll
            for (int m = 0; m < 2; ++m)
                #pragma unroll
                for (int kc = 0; kc < 16; ++kc)
                    if (kc >= kstart)
                        wf[m][kc] = *(const bf16x8*)(wb + (size_t)(m * 16 + kc) * 512);
        }

        f32x16 acc[2][2];
        #pragma unroll
        for (int m = 0; m < 2; ++m)
            #pragma unroll
            for (int tf = 0; tf < 2; ++tf)
                #pragma unroll
                for (int j = 0; j < 16; ++j) acc[m][tf][j] = 0.f;

        #pragma unroll
        for (int ks = 0; ks < 16; ++ks) {
            if (ks < kstart) continue;          // compile-time (d unrolled)
            int wo = ks * 32 + hi16;
            bf16x8 b0 = *(const bf16x8*)(Ab + swz(tok0, wo));
            bf16x8 b1 = *(const bf16x8*)(Ab + swz(tok1, wo));
            acc[0][0] = __builtin_amdgcn_mfma_f32_32x32x16_bf16(wf[0][ks], b0, acc[0][0], 0, 0, 0);
            acc[0][1] = __builtin_amdgcn_mfma_f32_32x32x16_bf16(wf[0][ks], b1, acc[0][1], 0, 0, 0);
            acc[1][0] = __builtin_amdgcn_mfma_f32_32x32x16_bf16(wf[1][ks], b0, acc[1][0], 0, 0, 0);
            acc[1][1] = __builtin_amdgcn_mfma_f32_32x32x16_bf16(wf[1][ks], b1, acc[1][1], 0, 0, 0);
        }
        __syncthreads();   // all Ab reads of this layer done before cur overwrite

        // ---- epilogue: bias+relu (fp32), estimator dot, cur -> Ab (bf16) ----
        // D[n][token]: token = lane&31, n = (reg&3) + 8*(reg>>2) + 4*hi (+32m+64nw)
        float p0 = 0.f, p1 = 0.f;
        #pragma unroll
        for (int m = 0; m < 2; ++m) {
            #pragma unroll
            for (int rg = 0; rg < 4; ++rg) {
                int nb = nw * 64 + m * 32 + rg * 8 + hi * 4;
                f4 bv = *(const f4*)(bl + d * D_ + nb);
                f4 ev = *(const f4*)(We + d * D_ + nb);
                #pragma unroll
                for (int tf = 0; tf < 2; ++tf) {
                    float c0 = fmaxf(acc[m][tf][rg * 4 + 0] + bv[0], 0.f);
                    float c1 = fmaxf(acc[m][tf][rg * 4 + 1] + bv[1], 0.f);
                    float c2 = fmaxf(acc[m][tf][rg * 4 + 2] + bv[2], 0.f);
                    float c3 = fmaxf(acc[m][tf][rg * 4 + 3] + bv[3], 0.f);
                    float pp = c0 * ev[0] + c1 * ev[1] + c2 * ev[2] + c3 * ev[3];
                    if (tf == 0) p0 += pp; else p1 += pp;
                    if (d < LAYERS - 1) {
                        bf16x4 cc;
                        cc[0] = (__bf16)c0; cc[1] = (__bf16)c1;
                        cc[2] = (__bf16)c2; cc[3] = (__bf16)c3;
                        int token = tw * 64 + tf * 32 + lo5;
                        *(bf16x4*)(Ab + swz(token, nb * 2)) = cc;
                    }
                }
            }
        }
        p0 += __shfl_xor(p0, 32, 64);
        p1 += __shfl_xor(p1, 32, 64);
        if (lane < 32) {
            PR[nw][tw * 64 + lo5]      = p0;
            PR[nw][tw * 64 + 32 + lo5] = p1;
        }
        __syncthreads();   // cur + PR (and, for d=0, CSM) visible

        if (t < BM)
            outc += CSM[t][d] * (PR[0][t] + PR[1][t] + be[d]);
    }

    if (t < BM) out[m0 + t] = outc;
}

extern "C" void kernel_launch(void* const* d_in, const int* in_sizes, int n_in,
                              void* d_out, int out_size, void* d_ws, size_t ws_size,
                              hipStream_t stream) {
    const float* x  = (const float*)d_in[0];
    const float* Wr = (const float*)d_in[1];
    const float* Wl = (const float*)d_in[2];
    const float* bl = (const float*)d_in[3];
    const float* We = (const float*)d_in[4];
    const float* be = (const float*)d_in[5];
    float* out = (float*)d_out;
    __bf16* wt2 = (__bf16*)d_ws;                // 256 KB scratch
    const int B = in_sizes[0] / D_;             // 131072

    prep<<<dim3(512), dim3(256), 0, stream>>>(Wl, wt2);
    moe_fwd<<<dim3(B / BM), dim3(NT), 0, stream>>>(x, Wr, wt2, bl, We, be, out);
}

// Round 5
// 54.273 us; speedup vs baseline: 8.4347x; 1.0387x over previous
//
#include <hip/hip_runtime.h>
#include <cstddef>

typedef float f4 __attribute__((ext_vector_type(4)));
typedef __bf16 bf16x8 __attribute__((ext_vector_type(8)));
typedef __bf16 bf16x4 __attribute__((ext_vector_type(4)));
typedef float f32x16 __attribute__((ext_vector_type(16)));

constexpr int D_ = 128;     // d_model
constexpr int LAYERS = 4;
constexpr int BM = 128;     // tokens per block
constexpr int NT = 512;     // 8 waves: 4 nf (32-n frags) x 2 tw (64-token halves)
constexpr int ROWB = 512;   // A-tile row stride bytes (256 bf16)

// XOR swizzle (T2/G4): spreads 16B slots across banks for stride-512B rows.
__device__ __forceinline__ int swz(int row, int woff) {
    return row * ROWB + (woff ^ ((row & 15) << 4));
}

// prep: W^T in MFMA A-fragment order.
// wt2[((d*4 + nf)*16 + kc)*512 + lane*8 + j] = W^T[d][n = nf*32 + (lane&31)]
//                                                  [k = kc*16 + (lane>>5)*8 + j]
// Layer 0 folds concat([x,x]): top+bot summed into k in [128,256), zeros below.
__global__ void prep(const float* __restrict__ Wl, __bf16* __restrict__ wt2) {
    int idx = blockIdx.x * 256 + threadIdx.x;        // 4*4*16*512 = 131072
    int j = idx & 7, lane = (idx >> 3) & 63, kc = (idx >> 9) & 15,
        nf = (idx >> 13) & 3, d = idx >> 15;
    int n  = nf * 32 + (lane & 31);
    int ks = kc * 16 + (lane >> 5) * 8 + j;
    float v;
    if (d == 0)
        v = (ks < 128) ? 0.f
                       : (Wl[(size_t)(ks - 128) * D_ + n] + Wl[(size_t)ks * D_ + n]);
    else
        v = Wl[(size_t)d * 2 * D_ * D_ + (size_t)ks * D_ + n];
    wt2[idx] = (__bf16)v;
}

__global__ __launch_bounds__(NT, 4)   // 4 waves/SIMD -> VGPR capped at 128
void moe_fwd(const float* __restrict__ x, const float* __restrict__ Wr,
             const __bf16* __restrict__ wt2, const float* __restrict__ bl,
             const float* __restrict__ We, const float* __restrict__ be,
             float* __restrict__ out)
{
    __shared__ char Ab[BM * ROWB];     // 64 KB: [token][256 k] bf16 swizzled (k<128 cur, k>=128 x)
    __shared__ float PR[4][BM];        // per-nf estimator partials
    __shared__ float CSM[BM][4];       // per-token 0/1 gate coefs

    const int t    = threadIdx.x;
    const int m0   = blockIdx.x * BM;
    const int lane = t & 63, w = t >> 6;
    const int nf   = w >> 1;            // 0..3: n in [nf*32, nf*32+32)
    const int tw   = w & 1;             // 0..1: token half
    const int lo5  = lane & 31, hi = lane >> 5;
    const int hi16 = hi * 16;
    const int tok0 = tw * 64 + lo5, tok1 = tok0 + 32;
    const int grp  = t >> 4, il = t & 15;   // 16 lanes per token row

    // ---- per-lane Wr rows (k = il*8 .. il*8+7), held in regs for gate dots ----
    f4 wrv[8];
    #pragma unroll
    for (int j = 0; j < 8; ++j)
        wrv[j] = *(const f4*)(Wr + (il * 8 + j) * 4);

    // ---- fused: stage x -> Ab (bf16, swizzled) + f64 gates from same registers ----
    // iteration i: this thread handles token row 32i + grp, cols il*8 .. il*8+7.
    #pragma unroll
    for (int i = 0; i < 4; ++i) {
        const int row = i * 32 + grp;
        const f4* gx = (const f4*)(x + (size_t)(m0 + row) * D_ + il * 8);
        f4 lo = gx[0], hp = gx[1];
        bf16x8 v;
        v[0] = (__bf16)lo[0]; v[1] = (__bf16)lo[1]; v[2] = (__bf16)lo[2]; v[3] = (__bf16)lo[3];
        v[4] = (__bf16)hp[0]; v[5] = (__bf16)hp[1]; v[6] = (__bf16)hp[2]; v[7] = (__bf16)hp[3];
        *(bf16x8*)(Ab + swz(row, 256 + il * 16)) = v;

        double a0 = 0, a1 = 0, a2 = 0, a3 = 0;
        #pragma unroll
        for (int j = 0; j < 4; ++j) {
            double xv = (double)lo[j];
            a0 += xv * (double)wrv[j][0]; a1 += xv * (double)wrv[j][1];
            a2 += xv * (double)wrv[j][2]; a3 += xv * (double)wrv[j][3];
        }
        #pragma unroll
        for (int j = 0; j < 4; ++j) {
            double xv = (double)hp[j];
            a0 += xv * (double)wrv[4 + j][0]; a1 += xv * (double)wrv[4 + j][1];
            a2 += xv * (double)wrv[4 + j][2]; a3 += xv * (double)wrv[4 + j][3];
        }
        #pragma unroll
        for (int s = 1; s < 16; s <<= 1) {   // 16-lane f64 tree reduce
            a0 += __shfl_xor(a0, s, 16);
            a1 += __shfl_xor(a1, s, 16);
            a2 += __shfl_xor(a2, s, 16);
            a3 += __shfl_xor(a3, s, 16);
        }
        if (il == 0) {
            f4 c;
            c[0] = a0 > 0.0 ? 1.f : 0.f; c[1] = a1 > 0.0 ? 1.f : 0.f;
            c[2] = a2 > 0.0 ? 1.f : 0.f; c[3] = a3 > 0.0 ? 1.f : 0.f;
            *(f4*)(&CSM[row][0]) = c;
        }
    }

    float outc = 0.f;
    __syncthreads();

    #pragma unroll
    for (int d = 0; d < LAYERS; ++d) {
        const int kstart = (d == 0) ? 8 : 0;   // layer 0: K=128 (x half only)

        // ---- A-operand (W^T) frags for this wave's 32-n block: L2 -> regs ----
        bf16x8 wf[16];
        {
            const __bf16* wb = wt2 + ((size_t)(d * 4 + nf) * 16) * 512 + lane * 8;
            #pragma unroll
            for (int kc = 0; kc < 16; ++kc)
                if (kc >= kstart)
                    wf[kc] = *(const bf16x8*)(wb + (size_t)kc * 512);
        }

        f32x16 acc[2];
        #pragma unroll
        for (int tf = 0; tf < 2; ++tf)
            #pragma unroll
            for (int j = 0; j < 16; ++j) acc[tf][j] = 0.f;

        #pragma unroll
        for (int ks = 0; ks < 16; ++ks) {
            if (ks < kstart) continue;          // compile-time (d unrolled)
            int wo = ks * 32 + hi16;
            bf16x8 b0 = *(const bf16x8*)(Ab + swz(tok0, wo));
            bf16x8 b1 = *(const bf16x8*)(Ab + swz(tok1, wo));
            acc[0] = __builtin_amdgcn_mfma_f32_32x32x16_bf16(wf[ks], b0, acc[0], 0, 0, 0);
            acc[1] = __builtin_amdgcn_mfma_f32_32x32x16_bf16(wf[ks], b1, acc[1], 0, 0, 0);
        }
        __syncthreads();   // all Ab reads of this layer done before cur overwrite

        // ---- epilogue: bias+relu (fp32), estimator dot, cur -> Ab (bf16) ----
        // D[n][token]: token = lane&31, n = (reg&3) + 8*(reg>>2) + 4*hi (+32*nf)
        float p0 = 0.f, p1 = 0.f;
        #pragma unroll
        for (int rg = 0; rg < 4; ++rg) {
            int nb = nf * 32 + rg * 8 + hi * 4;
            f4 bv = *(const f4*)(bl + d * D_ + nb);
            f4 ev = *(const f4*)(We + d * D_ + nb);
            #pragma unroll
            for (int tf = 0; tf < 2; ++tf) {
                float c0 = fmaxf(acc[tf][rg * 4 + 0] + bv[0], 0.f);
                float c1 = fmaxf(acc[tf][rg * 4 + 1] + bv[1], 0.f);
                float c2 = fmaxf(acc[tf][rg * 4 + 2] + bv[2], 0.f);
                float c3 = fmaxf(acc[tf][rg * 4 + 3] + bv[3], 0.f);
                float pp = c0 * ev[0] + c1 * ev[1] + c2 * ev[2] + c3 * ev[3];
                if (tf == 0) p0 += pp; else p1 += pp;
                if (d < LAYERS - 1) {
                    bf16x4 cc;
                    cc[0] = (__bf16)c0; cc[1] = (__bf16)c1;
                    cc[2] = (__bf16)c2; cc[3] = (__bf16)c3;
                    int token = tw * 64 + tf * 32 + lo5;
                    *(bf16x4*)(Ab + swz(token, nb * 2)) = cc;
                }
            }
        }
        p0 += __shfl_xor(p0, 32, 64);
        p1 += __shfl_xor(p1, 32, 64);
        if (lane < 32) {
            PR[nf][tw * 64 + lo5]      = p0;
            PR[nf][tw * 64 + 32 + lo5] = p1;
        }
        __syncthreads();   // cur + PR (and, for d=0, CSM) visible

        if (t < BM)
            outc += CSM[t][d] * (PR[0][t] + PR[1][t] + PR[2][t] + PR[3][t] + be[d]);
    }

    if (t < BM) out[m0 + t] = outc;
}

extern "C" void kernel_launch(void* const* d_in, const int* in_sizes, int n_in,
                              void* d_out, int out_size, void* d_ws, size_t ws_size,
                              hipStream_t stream) {
    const float* x  = (const float*)d_in[0];
    const float* Wr = (const float*)d_in[1];
    const float* Wl = (const float*)d_in[2];
    const float* bl = (const float*)d_in[3];
    const float* We = (const float*)d_in[4];
    const float* be = (const float*)d_in[5];
    float* out = (float*)d_out;
    __bf16* wt2 = (__bf16*)d_ws;                // 256 KB scratch
    const int B = in_sizes[0] / D_;             // 131072

    prep<<<dim3(512), dim3(256), 0, stream>>>(Wl, wt2);
    moe_fwd<<<dim3(B / BM), dim3(NT), 0, stream>>>(x, Wr, wt2, bl, We, be, out);
}